// Round 3
// baseline (407.518 us; speedup 1.0000x reference)
//
#include <hip/hip_runtime.h>
#include <hip/hip_bf16.h>
#include <cfloat>
#include <climits>
#include <cstdint>

#define ALPHA 30.0f
#define KSEL 16          // threshold = sorted[:,16] (17th smallest off-diag)
#define P0 1.38f         // candidate cutoff (data: d ~ 1.414 +- 0.022, rank17 ~ 1.356)
#define CANDCAP 512

typedef __attribute__((ext_vector_type(8))) short bf16x8;
typedef __attribute__((ext_vector_type(4))) float f32x4;

#define LDS_PTR(p) ((__attribute__((address_space(3))) uint32_t*)(p))
#define GLB_PTR(p) ((const __attribute__((address_space(1))) uint32_t*)(p))

// ---------------------------------------------------------------------------
// block reduce helpers (256 threads, 4 waves)
// ---------------------------------------------------------------------------
__device__ inline float blockReduceSumF(float v, float* s) {
    for (int off = 32; off; off >>= 1) v += __shfl_down(v, off);
    int tid = threadIdx.x, wid = tid >> 6;
    if ((tid & 63) == 0) s[wid] = v;
    __syncthreads();
    float r;
    if (tid == 0) { r = s[0] + s[1] + s[2] + s[3]; s[0] = r; }
    __syncthreads();
    r = s[0];
    __syncthreads();
    return r;
}

__device__ inline int blockReduceSumI(int v, int* s) {
    for (int off = 32; off; off >>= 1) v += __shfl_down(v, off);
    int tid = threadIdx.x, wid = tid >> 6;
    if ((tid & 63) == 0) s[wid] = v;
    __syncthreads();
    int r;
    if (tid == 0) { r = s[0] + s[1] + s[2] + s[3]; s[0] = r; }
    __syncthreads();
    r = s[0];
    __syncthreads();
    return r;
}

__device__ inline int blockReduceMinI(int v, int* s) {
    for (int off = 32; off; off >>= 1) v = min(v, __shfl_down(v, off));
    int tid = threadIdx.x, wid = tid >> 6;
    if ((tid & 63) == 0) s[wid] = v;
    __syncthreads();
    int r;
    if (tid == 0) { r = min(min(s[0], s[1]), min(s[2], s[3])); s[0] = r; }
    __syncthreads();
    r = s[0];
    __syncthreads();
    return r;
}

__device__ inline int blockReduceMaxI(int v, int* s) {
    for (int off = 32; off; off >>= 1) v = max(v, __shfl_down(v, off));
    int tid = threadIdx.x, wid = tid >> 6;
    if ((tid & 63) == 0) s[wid] = v;
    __syncthreads();
    int r;
    if (tid == 0) { r = max(max(s[0], s[1]), max(s[2], s[3])); s[0] = r; }
    __syncthreads();
    r = s[0];
    __syncthreads();
    return r;
}

// ---------------------------------------------------------------------------
// Kernel 1: fused fp32->bf16 (RNE) + per-row squared norm. One row per block.
// ---------------------------------------------------------------------------
__global__ __launch_bounds__(256) void prep_kernel(const float* __restrict__ X,
                                                   ushort* __restrict__ Xb,
                                                   float* __restrict__ sq, int D) {
    int row = blockIdx.x;
    int tid = threadIdx.x;
    const float4* xr = reinterpret_cast<const float4*>(X + (size_t)row * D);
    ushort4* xo = reinterpret_cast<ushort4*>(Xb + (size_t)row * D);
    float s = 0.f;
    for (int c = tid; c < D / 4; c += 256) {
        float4 v = xr[c];
        s += v.x * v.x + v.y * v.y + v.z * v.z + v.w * v.w;
        ushort4 o;
        uint32_t b;
        b = __builtin_bit_cast(uint32_t, v.x); o.x = (ushort)((b + 0x7FFF + ((b >> 16) & 1)) >> 16);
        b = __builtin_bit_cast(uint32_t, v.y); o.y = (ushort)((b + 0x7FFF + ((b >> 16) & 1)) >> 16);
        b = __builtin_bit_cast(uint32_t, v.z); o.z = (ushort)((b + 0x7FFF + ((b >> 16) & 1)) >> 16);
        b = __builtin_bit_cast(uint32_t, v.w); o.w = (ushort)((b + 0x7FFF + ((b >> 16) & 1)) >> 16);
        xo[c] = o;
    }
    __shared__ float sw[4];
    for (int off = 32; off; off >>= 1) s += __shfl_down(s, off);
    int wid = tid >> 6;
    if ((tid & 63) == 0) sw[wid] = s;
    __syncthreads();
    if (tid == 0) sq[row] = sw[0] + sw[1] + sw[2] + sw[3];
}

// ---------------------------------------------------------------------------
// Kernel 2: bf16 MFMA dist-GEMM + fused candidate collection in epilogue.
// dist[i][j] = sqrt(max(sq_i + sq_j - 2*dot_bf16(x_i, x_j), 1e-12))
// Off-diagonal d < P0 are pushed to candList[row] (count in candCnt[row]).
// ---------------------------------------------------------------------------
#define GBM 128
#define GBK 32
__global__ __launch_bounds__(256) void distgemm_mfma(const ushort* __restrict__ Xb,
                                                     const float* __restrict__ sq,
                                                     float* __restrict__ dist,
                                                     float* __restrict__ candList,
                                                     int* __restrict__ candCnt,
                                                     int N, int D) {
    __shared__ ushort As[GBM * GBK];   // [row][k], 8 KB, linear (global_load_lds dest)
    __shared__ ushort Bs[GBM * GBK];

    int tid = threadIdx.x;
    int lane = tid & 63;
    int wave = tid >> 6;       // 0..3
    int waveR = wave >> 1;     // 0..1
    int waveC = wave & 1;      // 0..1

    int rowBase = blockIdx.y * GBM;
    int colBase = blockIdx.x * GBM;

    f32x4 acc[4][4];
#pragma unroll
    for (int m = 0; m < 4; ++m)
#pragma unroll
        for (int n2 = 0; n2 < 4; ++n2) {
            f32x4 z = {0.f, 0.f, 0.f, 0.f};
            acc[m][n2] = z;
        }

    for (int k0 = 0; k0 < D; k0 += GBK) {
#pragma unroll
        for (int p = 0; p < 2; ++p) {
            int c = wave + 4 * p;                 // 0..7
            int byteoff = c * 1024 + lane * 16;   // within tile
            int r  = byteoff >> 6;                // row (64B per row)
            int kk = (byteoff & 63) >> 1;         // bf16 index within row
            const ushort* gA = Xb + (size_t)(rowBase + r) * D + k0 + kk;
            const ushort* gB = Xb + (size_t)(colBase + r) * D + k0 + kk;
            __builtin_amdgcn_global_load_lds(GLB_PTR(gA), LDS_PTR(As + c * 512), 16, 0, 0);
            __builtin_amdgcn_global_load_lds(GLB_PTR(gB), LDS_PTR(Bs + c * 512), 16, 0, 0);
        }
        __syncthreads();

        bf16x8 aF[4], bF[4];
        int chunk = (lane >> 4) * 8;
#pragma unroll
        for (int m = 0; m < 4; ++m) {
            int rl = waveR * 64 + m * 16 + (lane & 15);
            aF[m] = *reinterpret_cast<const bf16x8*>(&As[rl * GBK + chunk]);
        }
#pragma unroll
        for (int n2 = 0; n2 < 4; ++n2) {
            int rl = waveC * 64 + n2 * 16 + (lane & 15);
            bF[n2] = *reinterpret_cast<const bf16x8*>(&Bs[rl * GBK + chunk]);
        }
#pragma unroll
        for (int m = 0; m < 4; ++m)
#pragma unroll
            for (int n2 = 0; n2 < 4; ++n2)
                acc[m][n2] = __builtin_amdgcn_mfma_f32_16x16x32_bf16(aF[m], bF[n2], acc[m][n2], 0, 0, 0);
        __syncthreads();
    }

    // epilogue: C/D map col=lane&15, row=(lane>>4)*4+reg
    int cr = (lane >> 4) * 4;
    int cc = lane & 15;
#pragma unroll
    for (int m = 0; m < 4; ++m) {
#pragma unroll
        for (int n2 = 0; n2 < 4; ++n2) {
            int gcol = colBase + waveC * 64 + n2 * 16 + cc;
            float sqc = sq[gcol];
#pragma unroll
            for (int r = 0; r < 4; ++r) {
                int grow = rowBase + waveR * 64 + m * 16 + cr + r;
                float v = sq[grow] + sqc - 2.0f * acc[m][n2][r];
                float d = sqrtf(fmaxf(v, 1e-12f));
                dist[(size_t)grow * N + gcol] = d;
                if (d < P0 && gcol != grow) {
                    int p = atomicAdd(&candCnt[grow], 1);
                    if (p < CANDCAP) candList[(size_t)grow * CANDCAP + p] = d;
                }
            }
        }
    }
}

// ---------------------------------------------------------------------------
// Kernel 3: per-row threshold. Fast path: exact rank-KSEL among candidates
// (complete iff KSEL+1 <= cnt <= CANDCAP). Fallback: exact bitwise binary
// search over the full row (data-independent correctness).
// ---------------------------------------------------------------------------
__global__ __launch_bounds__(256) void select_thr_kernel(const float* __restrict__ dist,
                                                         const float* __restrict__ candList,
                                                         const int* __restrict__ candCnt,
                                                         float* __restrict__ thrArr, int N) {
    __shared__ float cv[CANDCAP];
    __shared__ int sI[4];
    __shared__ float s_thr;
    int row = blockIdx.x;
    int tid = threadIdx.x;
    int cnt = candCnt[row];

    if (cnt >= KSEL + 1 && cnt <= CANDCAP) {
        for (int e = tid; e < cnt; e += 256) cv[e] = candList[(size_t)row * CANDCAP + e];
        __syncthreads();
        // exact rank KSEL under (value, slot) total order -> 17th smallest value
        for (int e = tid; e < cnt; e += 256) {
            float v = cv[e];
            int r = 0;
            for (int q = 0; q < cnt; ++q) {
                float u = cv[q];
                r += (u < v) || (u == v && q < e);
            }
            if (r == KSEL) s_thr = v;
        }
        __syncthreads();
        if (tid == 0) thrArr[row] = s_thr;
    } else {
        // exact: find smallest u with count(bits(d) <= u) >= KSEL+1
        const float* drow = dist + (size_t)row * N;
        uint32_t lo = 0, hi = 0x40800000u;   // 4.0f; all dist < 2.01
        while (lo < hi) {
            uint32_t mid = (lo + hi) >> 1;
            float mv = __builtin_bit_cast(float, mid);
            int c = 0;
            for (int j = tid; j < N; j += 256)
                if (j != row && drow[j] <= mv) ++c;
            c = blockReduceSumI(c, sI);
            if (c >= KSEL + 1) hi = mid; else lo = mid + 1;
        }
        if (tid == 0) thrArr[row] = __builtin_bit_cast(float, hi);
    }
}

// ---------------------------------------------------------------------------
// Kernel 4: streaming masked sums per row (minimal LDS -> high occupancy)
// ---------------------------------------------------------------------------
__global__ __launch_bounds__(256) void sums_kernel(const float* __restrict__ dist,
                                                   const int* __restrict__ targets,
                                                   const float* __restrict__ thrArr,
                                                   float* __restrict__ accum, int N) {
    __shared__ float sF[4];
    __shared__ int sI[4];
    int row = blockIdx.x;
    int tid = threadIdx.x;
    const float* drow = dist + (size_t)row * N;
    float thr = thrArr[row];
    int ti = targets[row];

    float posS = 0.f, negS = 0.f;
    int firstPos = INT_MAX, anyNeg = 0, anyPosBelow = 0;
    for (int j = tid; j < N; j += 256) {
        if (j == row) continue;
        float d = drow[j];
        bool same = (targets[j] == ti);
        if (same) { if (j < firstPos) firstPos = j; }
        else anyNeg = 1;
        if (d < thr) {
            float e = expf(ALPHA * (1.0f - d));
            if (same) { posS += e; anyPosBelow = 1; }
            else negS += e;
        }
    }
    posS = blockReduceSumF(posS, sF);
    negS = blockReduceSumF(negS, sF);
    firstPos = blockReduceMinI(firstPos, sI);
    anyNeg = blockReduceMaxI(anyNeg, sI);
    anyPosBelow = blockReduceMaxI(anyPosBelow, sI);

    if (tid == 0) {
        bool anyPos = (firstPos != INT_MAX);
        if (anyPos && anyNeg) {
            float posLogit = anyPosBelow ? posS
                                         : expf(ALPHA * (1.0f - drow[firstPos]));
            float loss_i = -logf(posLogit / (posLogit + negS));
            atomicAdd(accum + 0, loss_i);
            atomicAdd(accum + 1, 1.0f);
            if (loss_i < 0.6f) atomicAdd(accum + 2, 1.0f);
        }
    }
}

// ---------------------------------------------------------------------------
// Kernel 5: finalize scalars
// ---------------------------------------------------------------------------
__global__ void finalize_kernel(const float* __restrict__ accum,
                                float* __restrict__ out, float n) {
    if (threadIdx.x == 0 && blockIdx.x == 0) {
        float nv = accum[1];
        out[0] = (nv > 0.f) ? accum[0] / nv : 0.f;
        out[1] = accum[2] / n;
        out[2] = 0.f;
        out[3] = 0.f;
    }
}

// ---------------------------------------------------------------------------
extern "C" void kernel_launch(void* const* d_in, const int* in_sizes, int n_in,
                              void* d_out, int out_size, void* d_ws, size_t ws_size,
                              hipStream_t stream) {
    const float* X = (const float*)d_in[0];
    const int* targets = (const int*)d_in[1];
    float* out = (float*)d_out;

    int N = in_sizes[1];             // 4096
    int D = in_sizes[0] / N;         // 1024

    float* dist     = (float*)d_ws;                      // N*N f32        (64 MB)
    float* sq       = dist + (size_t)N * N;              // N f32
    float* thrArr   = sq + N;                            // N f32
    float* accum    = thrArr + N;                        // 8 f32
    int*   candCnt  = (int*)(accum + 8);                 // N i32
    ushort* Xb      = (ushort*)(candCnt + N);            // N*D bf16       (8 MB)
    float* candList = (float*)(Xb + (size_t)N * D);      // N*CANDCAP f32  (8 MB)

    hipMemsetAsync(accum, 0, 8 * sizeof(float), stream);
    hipMemsetAsync(candCnt, 0, N * sizeof(int), stream);

    prep_kernel<<<N, 256, 0, stream>>>(X, Xb, sq, D);

    dim3 grid(N / GBM, N / GBM);
    distgemm_mfma<<<grid, 256, 0, stream>>>(Xb, sq, dist, candList, candCnt, N, D);

    select_thr_kernel<<<N, 256, 0, stream>>>(dist, candList, candCnt, thrArr, N);

    sums_kernel<<<N, 256, 0, stream>>>(dist, targets, thrArr, accum, N);

    finalize_kernel<<<1, 64, 0, stream>>>(accum, out, (float)N);
}

// Round 4
// 233.451 us; speedup vs baseline: 1.7456x; 1.7456x over previous
//
#include <hip/hip_runtime.h>
#include <hip/hip_bf16.h>
#include <cfloat>
#include <climits>
#include <cstdint>

#define ALPHA 30.0f
#define KSEL 16          // threshold = sorted[:,16] (17th smallest off-diag)
#define P0 1.38f         // candidate cutoff (d ~ 1.414 +- 0.022; rank-17 quantile ~1.356)
#define CANDCAP 512
#define BIGV 1e30f

typedef __attribute__((ext_vector_type(8))) short bf16x8;
typedef __attribute__((ext_vector_type(4))) float f32x4;

#define LDS_PTR(p) ((__attribute__((address_space(3))) uint32_t*)(p))
#define GLB_PTR(p) ((const __attribute__((address_space(1))) uint32_t*)(p))

// ---------------------------------------------------------------------------
// block reduce helpers (256 threads, 4 waves)
// ---------------------------------------------------------------------------
__device__ inline float blockReduceSumF(float v, float* s) {
    for (int off = 32; off; off >>= 1) v += __shfl_down(v, off);
    int tid = threadIdx.x, wid = tid >> 6;
    if ((tid & 63) == 0) s[wid] = v;
    __syncthreads();
    float r;
    if (tid == 0) { r = s[0] + s[1] + s[2] + s[3]; s[0] = r; }
    __syncthreads();
    r = s[0];
    __syncthreads();
    return r;
}

__device__ inline int blockReduceSumI(int v, int* s) {
    for (int off = 32; off; off >>= 1) v += __shfl_down(v, off);
    int tid = threadIdx.x, wid = tid >> 6;
    if ((tid & 63) == 0) s[wid] = v;
    __syncthreads();
    int r;
    if (tid == 0) { r = s[0] + s[1] + s[2] + s[3]; s[0] = r; }
    __syncthreads();
    r = s[0];
    __syncthreads();
    return r;
}

__device__ inline int blockReduceMinI(int v, int* s) {
    for (int off = 32; off; off >>= 1) v = min(v, __shfl_down(v, off));
    int tid = threadIdx.x, wid = tid >> 6;
    if ((tid & 63) == 0) s[wid] = v;
    __syncthreads();
    int r;
    if (tid == 0) { r = min(min(s[0], s[1]), min(s[2], s[3])); s[0] = r; }
    __syncthreads();
    r = s[0];
    __syncthreads();
    return r;
}

__device__ inline int blockReduceMaxI(int v, int* s) {
    for (int off = 32; off; off >>= 1) v = max(v, __shfl_down(v, off));
    int tid = threadIdx.x, wid = tid >> 6;
    if ((tid & 63) == 0) s[wid] = v;
    __syncthreads();
    int r;
    if (tid == 0) { r = max(max(s[0], s[1]), max(s[2], s[3])); s[0] = r; }
    __syncthreads();
    r = s[0];
    __syncthreads();
    return r;
}

// ---------------------------------------------------------------------------
// Kernel 1: fused fp32->bf16 (RNE) + per-row squared norm. One row per block.
// ---------------------------------------------------------------------------
__global__ __launch_bounds__(256) void prep_kernel(const float* __restrict__ X,
                                                   ushort* __restrict__ Xb,
                                                   float* __restrict__ sq, int D) {
    int row = blockIdx.x;
    int tid = threadIdx.x;
    const float4* xr = reinterpret_cast<const float4*>(X + (size_t)row * D);
    ushort4* xo = reinterpret_cast<ushort4*>(Xb + (size_t)row * D);
    float s = 0.f;
    for (int c = tid; c < D / 4; c += 256) {
        float4 v = xr[c];
        s += v.x * v.x + v.y * v.y + v.z * v.z + v.w * v.w;
        ushort4 o;
        uint32_t b;
        b = __builtin_bit_cast(uint32_t, v.x); o.x = (ushort)((b + 0x7FFF + ((b >> 16) & 1)) >> 16);
        b = __builtin_bit_cast(uint32_t, v.y); o.y = (ushort)((b + 0x7FFF + ((b >> 16) & 1)) >> 16);
        b = __builtin_bit_cast(uint32_t, v.z); o.z = (ushort)((b + 0x7FFF + ((b >> 16) & 1)) >> 16);
        b = __builtin_bit_cast(uint32_t, v.w); o.w = (ushort)((b + 0x7FFF + ((b >> 16) & 1)) >> 16);
        xo[c] = o;
    }
    __shared__ float sw[4];
    for (int off = 32; off; off >>= 1) s += __shfl_down(s, off);
    int wid = tid >> 6;
    if ((tid & 63) == 0) sw[wid] = s;
    __syncthreads();
    if (tid == 0) sq[row] = sw[0] + sw[1] + sw[2] + sw[3];
}

// ---------------------------------------------------------------------------
// Kernel 2: bf16 MFMA dist-GEMM (clean R2 version; coalesced stores only).
// dist[i][j] = sqrt(max(sq_i + sq_j - 2*dot_bf16(x_i, x_j), 1e-12))
// ---------------------------------------------------------------------------
#define GBM 128
#define GBK 32
__global__ __launch_bounds__(256) void distgemm_mfma(const ushort* __restrict__ Xb,
                                                     const float* __restrict__ sq,
                                                     float* __restrict__ dist,
                                                     int N, int D) {
    __shared__ ushort As[GBM * GBK];   // [row][k], 8 KB, linear (global_load_lds dest)
    __shared__ ushort Bs[GBM * GBK];

    int tid = threadIdx.x;
    int lane = tid & 63;
    int wave = tid >> 6;       // 0..3
    int waveR = wave >> 1;     // 0..1
    int waveC = wave & 1;      // 0..1

    int rowBase = blockIdx.y * GBM;
    int colBase = blockIdx.x * GBM;

    f32x4 acc[4][4];
#pragma unroll
    for (int m = 0; m < 4; ++m)
#pragma unroll
        for (int n2 = 0; n2 < 4; ++n2) {
            f32x4 z = {0.f, 0.f, 0.f, 0.f};
            acc[m][n2] = z;
        }

    for (int k0 = 0; k0 < D; k0 += GBK) {
#pragma unroll
        for (int p = 0; p < 2; ++p) {
            int c = wave + 4 * p;                 // 0..7
            int byteoff = c * 1024 + lane * 16;   // within tile
            int r  = byteoff >> 6;                // row (64B per row)
            int kk = (byteoff & 63) >> 1;         // bf16 index within row
            const ushort* gA = Xb + (size_t)(rowBase + r) * D + k0 + kk;
            const ushort* gB = Xb + (size_t)(colBase + r) * D + k0 + kk;
            __builtin_amdgcn_global_load_lds(GLB_PTR(gA), LDS_PTR(As + c * 512), 16, 0, 0);
            __builtin_amdgcn_global_load_lds(GLB_PTR(gB), LDS_PTR(Bs + c * 512), 16, 0, 0);
        }
        __syncthreads();

        bf16x8 aF[4], bF[4];
        int chunk = (lane >> 4) * 8;
#pragma unroll
        for (int m = 0; m < 4; ++m) {
            int rl = waveR * 64 + m * 16 + (lane & 15);
            aF[m] = *reinterpret_cast<const bf16x8*>(&As[rl * GBK + chunk]);
        }
#pragma unroll
        for (int n2 = 0; n2 < 4; ++n2) {
            int rl = waveC * 64 + n2 * 16 + (lane & 15);
            bF[n2] = *reinterpret_cast<const bf16x8*>(&Bs[rl * GBK + chunk]);
        }
#pragma unroll
        for (int m = 0; m < 4; ++m)
#pragma unroll
            for (int n2 = 0; n2 < 4; ++n2)
                acc[m][n2] = __builtin_amdgcn_mfma_f32_16x16x32_bf16(aF[m], bF[n2], acc[m][n2], 0, 0, 0);
        __syncthreads();
    }

    // epilogue: C/D map col=lane&15, row=(lane>>4)*4+reg
    int cr = (lane >> 4) * 4;
    int cc = lane & 15;
#pragma unroll
    for (int m = 0; m < 4; ++m) {
#pragma unroll
        for (int n2 = 0; n2 < 4; ++n2) {
            int gcol = colBase + waveC * 64 + n2 * 16 + cc;
            float sqc = sq[gcol];
#pragma unroll
            for (int r = 0; r < 4; ++r) {
                int grow = rowBase + waveR * 64 + m * 16 + cr + r;
                float v = sq[grow] + sqc - 2.0f * acc[m][n2][r];
                dist[(size_t)grow * N + gcol] = sqrtf(fmaxf(v, 1e-12f));
            }
        }
    }
}

// ---------------------------------------------------------------------------
// Kernel 3: fused per-row threshold + masked sums. One block per row.
// Row staged once in LDS (float4 loads). Candidates (< P0) compacted via
// wave-ballot (1 LDS atomic per wave-iter). Exact rank-16 among candidates;
// exact full-row bitwise binary-search fallback if cnt outside [17, CANDCAP].
// ---------------------------------------------------------------------------
#define NMAX 4096
__global__ __launch_bounds__(256) void rowfinal_kernel(const float* __restrict__ dist,
                                                       const int* __restrict__ targets,
                                                       float* __restrict__ accum, int N) {
    __shared__ float rowD[NMAX];      // 16 KB
    __shared__ float cand[CANDCAP];   // 2 KB
    __shared__ float sF[4];
    __shared__ int sI[4];
    __shared__ int s_cnt;
    __shared__ float s_thr;

    int row = blockIdx.x;
    int tid = threadIdx.x;
    int lane = tid & 63;
    const float* drow = dist + (size_t)row * N;

    // stage row in LDS, vectorized
    for (int c = tid; c < N / 4; c += 256) {
        float4 v = *reinterpret_cast<const float4*>(drow + c * 4);
        *reinterpret_cast<float4*>(&rowD[c * 4]) = v;
    }
    if (tid == 0) { s_cnt = 0; }
    __syncthreads();
    if (tid == 0) rowD[row] = BIGV;   // exclude diagonal from selection
    __syncthreads();

    // wave-ballot compaction of candidates < P0
    for (int j = tid; j < N; j += 256) {
        bool pred = rowD[j] < P0;
        unsigned long long mask = __ballot(pred);
        if (mask) {
            int leader = __ffsll((long long)mask) - 1;
            int tot = __popcll(mask);
            int base = 0;
            if (lane == leader) base = atomicAdd(&s_cnt, tot);
            base = __shfl(base, leader);
            if (pred) {
                int pre = __popcll(mask & ((1ull << lane) - 1ull));
                int p = base + pre;
                if (p < CANDCAP) cand[p] = rowD[j];
            }
        }
    }
    __syncthreads();

    int cnt = s_cnt;
    if (cnt >= KSEL + 1 && cnt <= CANDCAP) {
        // exact rank-KSEL among candidates (all non-candidates >= P0 > cand)
        for (int e = tid; e < cnt; e += 256) {
            float v = cand[e];
            int r = 0;
            for (int q = 0; q < cnt; ++q) {
                float u = cand[q];
                r += (u < v) || (u == v && q < e);
            }
            if (r == KSEL) s_thr = v;
        }
        __syncthreads();
    } else {
        // exact fallback: smallest float u with count(rowD <= u) >= KSEL+1
        uint32_t lo = 0, hi = 0x40800000u;   // 4.0f; all real dist < 2.01
        while (lo < hi) {
            uint32_t mid = (lo + hi) >> 1;
            float mv = __builtin_bit_cast(float, mid);
            int c = 0;
            for (int j = tid; j < N; j += 256)
                c += (rowD[j] <= mv);        // diag is BIGV, auto-excluded
            c = blockReduceSumI(c, sI);
            if (c >= KSEL + 1) hi = mid; else lo = mid + 1;
        }
        if (tid == 0) s_thr = __builtin_bit_cast(float, hi);
        __syncthreads();
    }
    float thr = s_thr;

    // masked sums from LDS
    int ti = targets[row];
    float posS = 0.f, negS = 0.f;
    int firstPos = INT_MAX, anyNeg = 0, anyPosBelow = 0;
    for (int j = tid; j < N; j += 256) {
        if (j == row) continue;
        float d = rowD[j];
        bool same = (targets[j] == ti);
        if (same) { if (j < firstPos) firstPos = j; }
        else anyNeg = 1;
        if (d < thr) {
            float e = expf(ALPHA * (1.0f - d));
            if (same) { posS += e; anyPosBelow = 1; }
            else negS += e;
        }
    }
    posS = blockReduceSumF(posS, sF);
    negS = blockReduceSumF(negS, sF);
    firstPos = blockReduceMinI(firstPos, sI);
    anyNeg = blockReduceMaxI(anyNeg, sI);
    anyPosBelow = blockReduceMaxI(anyPosBelow, sI);

    if (tid == 0) {
        bool anyPos = (firstPos != INT_MAX);
        if (anyPos && anyNeg) {
            float posLogit = anyPosBelow ? posS
                                         : expf(ALPHA * (1.0f - rowD[firstPos]));
            float loss_i = -logf(posLogit / (posLogit + negS));
            atomicAdd(accum + 0, loss_i);
            atomicAdd(accum + 1, 1.0f);
            if (loss_i < 0.6f) atomicAdd(accum + 2, 1.0f);
        }
    }
}

// ---------------------------------------------------------------------------
// Kernel 4: finalize scalars
// ---------------------------------------------------------------------------
__global__ void finalize_kernel(const float* __restrict__ accum,
                                float* __restrict__ out, float n) {
    if (threadIdx.x == 0 && blockIdx.x == 0) {
        float nv = accum[1];
        out[0] = (nv > 0.f) ? accum[0] / nv : 0.f;
        out[1] = accum[2] / n;
        out[2] = 0.f;
        out[3] = 0.f;
    }
}

// ---------------------------------------------------------------------------
extern "C" void kernel_launch(void* const* d_in, const int* in_sizes, int n_in,
                              void* d_out, int out_size, void* d_ws, size_t ws_size,
                              hipStream_t stream) {
    const float* X = (const float*)d_in[0];
    const int* targets = (const int*)d_in[1];
    float* out = (float*)d_out;

    int N = in_sizes[1];             // 4096
    int D = in_sizes[0] / N;         // 1024

    float* dist  = (float*)d_ws;                      // N*N f32  (64 MB)
    float* sq    = dist + (size_t)N * N;              // N f32
    float* accum = sq + N;                            // 8 f32
    ushort* Xb   = (ushort*)(accum + 8);              // N*D bf16 (8 MB)

    hipMemsetAsync(accum, 0, 8 * sizeof(float), stream);

    prep_kernel<<<N, 256, 0, stream>>>(X, Xb, sq, D);

    dim3 grid(N / GBM, N / GBM);
    distgemm_mfma<<<grid, 256, 0, stream>>>(Xb, sq, dist, N, D);

    rowfinal_kernel<<<N, 256, 0, stream>>>(dist, targets, accum, N);

    finalize_kernel<<<1, 64, 0, stream>>>(accum, out, (float)N);
}

// Round 5
// 157.838 us; speedup vs baseline: 2.5819x; 1.4791x over previous
//
#include <hip/hip_runtime.h>
#include <hip/hip_bf16.h>
#include <cfloat>
#include <climits>
#include <cstdint>

#define ALPHA 30.0f
#define KSEL 16          // threshold = sorted[:,16] (17th smallest off-diag)
#define P0 1.38f         // candidate cutoff (d ~ 1.414 +- 0.022; rank-17 quantile ~1.356)
#define CANDCAP 512
#define BIGV 1e30f

typedef __attribute__((ext_vector_type(8))) short bf16x8;
typedef __attribute__((ext_vector_type(4))) float f32x4;

#define LDS_PTR(p) ((__attribute__((address_space(3))) uint32_t*)(p))
#define GLB_PTR(p) ((const __attribute__((address_space(1))) uint32_t*)(p))

// ---------------------------------------------------------------------------
// block reduce helpers (256 threads, 4 waves)
// ---------------------------------------------------------------------------
__device__ inline float blockReduceSumF(float v, float* s) {
    for (int off = 32; off; off >>= 1) v += __shfl_down(v, off);
    int tid = threadIdx.x, wid = tid >> 6;
    if ((tid & 63) == 0) s[wid] = v;
    __syncthreads();
    float r;
    if (tid == 0) { r = s[0] + s[1] + s[2] + s[3]; s[0] = r; }
    __syncthreads();
    r = s[0];
    __syncthreads();
    return r;
}

__device__ inline int blockReduceSumI(int v, int* s) {
    for (int off = 32; off; off >>= 1) v += __shfl_down(v, off);
    int tid = threadIdx.x, wid = tid >> 6;
    if ((tid & 63) == 0) s[wid] = v;
    __syncthreads();
    int r;
    if (tid == 0) { r = s[0] + s[1] + s[2] + s[3]; s[0] = r; }
    __syncthreads();
    r = s[0];
    __syncthreads();
    return r;
}

__device__ inline int blockReduceMinI(int v, int* s) {
    for (int off = 32; off; off >>= 1) v = min(v, __shfl_down(v, off));
    int tid = threadIdx.x, wid = tid >> 6;
    if ((tid & 63) == 0) s[wid] = v;
    __syncthreads();
    int r;
    if (tid == 0) { r = min(min(s[0], s[1]), min(s[2], s[3])); s[0] = r; }
    __syncthreads();
    r = s[0];
    __syncthreads();
    return r;
}

__device__ inline int blockReduceMaxI(int v, int* s) {
    for (int off = 32; off; off >>= 1) v = max(v, __shfl_down(v, off));
    int tid = threadIdx.x, wid = tid >> 6;
    if ((tid & 63) == 0) s[wid] = v;
    __syncthreads();
    int r;
    if (tid == 0) { r = max(max(s[0], s[1]), max(s[2], s[3])); s[0] = r; }
    __syncthreads();
    r = s[0];
    __syncthreads();
    return r;
}

// ---------------------------------------------------------------------------
// Kernel 1: fused fp32->bf16 (RNE) + per-row squared norm. One row per block.
// ---------------------------------------------------------------------------
__global__ __launch_bounds__(256) void prep_kernel(const float* __restrict__ X,
                                                   ushort* __restrict__ Xb,
                                                   float* __restrict__ sq, int D) {
    int row = blockIdx.x;
    int tid = threadIdx.x;
    const float4* xr = reinterpret_cast<const float4*>(X + (size_t)row * D);
    ushort4* xo = reinterpret_cast<ushort4*>(Xb + (size_t)row * D);
    float s = 0.f;
    for (int c = tid; c < D / 4; c += 256) {
        float4 v = xr[c];
        s += v.x * v.x + v.y * v.y + v.z * v.z + v.w * v.w;
        ushort4 o;
        uint32_t b;
        b = __builtin_bit_cast(uint32_t, v.x); o.x = (ushort)((b + 0x7FFF + ((b >> 16) & 1)) >> 16);
        b = __builtin_bit_cast(uint32_t, v.y); o.y = (ushort)((b + 0x7FFF + ((b >> 16) & 1)) >> 16);
        b = __builtin_bit_cast(uint32_t, v.z); o.z = (ushort)((b + 0x7FFF + ((b >> 16) & 1)) >> 16);
        b = __builtin_bit_cast(uint32_t, v.w); o.w = (ushort)((b + 0x7FFF + ((b >> 16) & 1)) >> 16);
        xo[c] = o;
    }
    __shared__ float sw[4];
    for (int off = 32; off; off >>= 1) s += __shfl_down(s, off);
    int wid = tid >> 6;
    if ((tid & 63) == 0) sw[wid] = s;
    __syncthreads();
    if (tid == 0) sq[row] = sw[0] + sw[1] + sw[2] + sw[3];
}

// ---------------------------------------------------------------------------
// Kernel 2: bf16 MFMA dist-GEMM (coalesced stores only).
// dist[i][j] = sqrt(max(sq_i + sq_j - 2*dot_bf16(x_i, x_j), 1e-12))
// ---------------------------------------------------------------------------
#define GBM 128
#define GBK 32
__global__ __launch_bounds__(256) void distgemm_mfma(const ushort* __restrict__ Xb,
                                                     const float* __restrict__ sq,
                                                     float* __restrict__ dist,
                                                     int N, int D) {
    __shared__ ushort As[GBM * GBK];   // [row][k], 8 KB, linear (global_load_lds dest)
    __shared__ ushort Bs[GBM * GBK];

    int tid = threadIdx.x;
    int lane = tid & 63;
    int wave = tid >> 6;       // 0..3
    int waveR = wave >> 1;     // 0..1
    int waveC = wave & 1;      // 0..1

    int rowBase = blockIdx.y * GBM;
    int colBase = blockIdx.x * GBM;

    f32x4 acc[4][4];
#pragma unroll
    for (int m = 0; m < 4; ++m)
#pragma unroll
        for (int n2 = 0; n2 < 4; ++n2) {
            f32x4 z = {0.f, 0.f, 0.f, 0.f};
            acc[m][n2] = z;
        }

    for (int k0 = 0; k0 < D; k0 += GBK) {
#pragma unroll
        for (int p = 0; p < 2; ++p) {
            int c = wave + 4 * p;                 // 0..7
            int byteoff = c * 1024 + lane * 16;   // within tile
            int r  = byteoff >> 6;                // row (64B per row)
            int kk = (byteoff & 63) >> 1;         // bf16 index within row
            const ushort* gA = Xb + (size_t)(rowBase + r) * D + k0 + kk;
            const ushort* gB = Xb + (size_t)(colBase + r) * D + k0 + kk;
            __builtin_amdgcn_global_load_lds(GLB_PTR(gA), LDS_PTR(As + c * 512), 16, 0, 0);
            __builtin_amdgcn_global_load_lds(GLB_PTR(gB), LDS_PTR(Bs + c * 512), 16, 0, 0);
        }
        __syncthreads();

        bf16x8 aF[4], bF[4];
        int chunk = (lane >> 4) * 8;
#pragma unroll
        for (int m = 0; m < 4; ++m) {
            int rl = waveR * 64 + m * 16 + (lane & 15);
            aF[m] = *reinterpret_cast<const bf16x8*>(&As[rl * GBK + chunk]);
        }
#pragma unroll
        for (int n2 = 0; n2 < 4; ++n2) {
            int rl = waveC * 64 + n2 * 16 + (lane & 15);
            bF[n2] = *reinterpret_cast<const bf16x8*>(&Bs[rl * GBK + chunk]);
        }
#pragma unroll
        for (int m = 0; m < 4; ++m)
#pragma unroll
            for (int n2 = 0; n2 < 4; ++n2)
                acc[m][n2] = __builtin_amdgcn_mfma_f32_16x16x32_bf16(aF[m], bF[n2], acc[m][n2], 0, 0, 0);
        __syncthreads();
    }

    // epilogue: C/D map col=lane&15, row=(lane>>4)*4+reg
    int cr = (lane >> 4) * 4;
    int cc = lane & 15;
#pragma unroll
    for (int m = 0; m < 4; ++m) {
#pragma unroll
        for (int n2 = 0; n2 < 4; ++n2) {
            int gcol = colBase + waveC * 64 + n2 * 16 + cc;
            float sqc = sq[gcol];
#pragma unroll
            for (int r = 0; r < 4; ++r) {
                int grow = rowBase + waveR * 64 + m * 16 + cr + r;
                float v = sq[grow] + sqc - 2.0f * acc[m][n2][r];
                dist[(size_t)grow * N + gcol] = sqrtf(fmaxf(v, 1e-12f));
            }
        }
    }
}

// ---------------------------------------------------------------------------
// Kernel 3: fused per-row threshold + masked sums. One block per row.
// NO global atomics: writes per-row loss (BIGV sentinel = invalid row).
// ---------------------------------------------------------------------------
#define NMAX 4096
__global__ __launch_bounds__(256) void rowfinal_kernel(const float* __restrict__ dist,
                                                       const int* __restrict__ targets,
                                                       float* __restrict__ rowLoss, int N) {
    __shared__ float rowD[NMAX];      // 16 KB
    __shared__ float cand[CANDCAP];   // 2 KB
    __shared__ float sF[4];
    __shared__ int sI[4];
    __shared__ int s_cnt;
    __shared__ float s_thr;

    int row = blockIdx.x;
    int tid = threadIdx.x;
    int lane = tid & 63;
    const float* drow = dist + (size_t)row * N;

    // stage row in LDS, vectorized
    for (int c = tid; c < N / 4; c += 256) {
        float4 v = *reinterpret_cast<const float4*>(drow + c * 4);
        *reinterpret_cast<float4*>(&rowD[c * 4]) = v;
    }
    if (tid == 0) { s_cnt = 0; }
    __syncthreads();
    if (tid == 0) rowD[row] = BIGV;   // exclude diagonal from selection
    __syncthreads();

    // wave-ballot compaction of candidates < P0
    for (int j = tid; j < N; j += 256) {
        bool pred = rowD[j] < P0;
        unsigned long long mask = __ballot(pred);
        if (mask) {
            int leader = __ffsll((long long)mask) - 1;
            int tot = __popcll(mask);
            int base = 0;
            if (lane == leader) base = atomicAdd(&s_cnt, tot);
            base = __shfl(base, leader);
            if (pred) {
                int pre = __popcll(mask & ((1ull << lane) - 1ull));
                int p = base + pre;
                if (p < CANDCAP) cand[p] = rowD[j];
            }
        }
    }
    __syncthreads();

    int cnt = s_cnt;
    if (cnt >= KSEL + 1 && cnt <= CANDCAP) {
        // exact rank-KSEL among candidates (all non-candidates >= P0 > cand)
        for (int e = tid; e < cnt; e += 256) {
            float v = cand[e];
            int r = 0;
            for (int q = 0; q < cnt; ++q) {
                float u = cand[q];
                r += (u < v) || (u == v && q < e);
            }
            if (r == KSEL) s_thr = v;
        }
        __syncthreads();
    } else {
        // exact fallback: smallest float u with count(rowD <= u) >= KSEL+1
        uint32_t lo = 0, hi = 0x40800000u;   // 4.0f; all real dist < 2.01
        while (lo < hi) {
            uint32_t mid = (lo + hi) >> 1;
            float mv = __builtin_bit_cast(float, mid);
            int c = 0;
            for (int j = tid; j < N; j += 256)
                c += (rowD[j] <= mv);        // diag is BIGV, auto-excluded
            c = blockReduceSumI(c, sI);
            if (c >= KSEL + 1) hi = mid; else lo = mid + 1;
        }
        if (tid == 0) s_thr = __builtin_bit_cast(float, hi);
        __syncthreads();
    }
    float thr = s_thr;

    // masked sums from LDS
    int ti = targets[row];
    float posS = 0.f, negS = 0.f;
    int firstPos = INT_MAX, anyNeg = 0, anyPosBelow = 0;
    for (int j = tid; j < N; j += 256) {
        if (j == row) continue;
        float d = rowD[j];
        bool same = (targets[j] == ti);
        if (same) { if (j < firstPos) firstPos = j; }
        else anyNeg = 1;
        if (d < thr) {
            float e = expf(ALPHA * (1.0f - d));
            if (same) { posS += e; anyPosBelow = 1; }
            else negS += e;
        }
    }
    posS = blockReduceSumF(posS, sF);
    negS = blockReduceSumF(negS, sF);
    firstPos = blockReduceMinI(firstPos, sI);
    anyNeg = blockReduceMaxI(anyNeg, sI);
    anyPosBelow = blockReduceMaxI(anyPosBelow, sI);

    if (tid == 0) {
        bool anyPos = (firstPos != INT_MAX);
        if (anyPos && anyNeg) {
            float posLogit = anyPosBelow ? posS
                                         : expf(ALPHA * (1.0f - rowD[firstPos]));
            rowLoss[row] = -logf(posLogit / (posLogit + negS));
        } else {
            rowLoss[row] = BIGV;   // invalid sentinel
        }
    }
}

// ---------------------------------------------------------------------------
// Kernel 4: single-block reduction over rowLoss -> out[4]
// ---------------------------------------------------------------------------
__global__ __launch_bounds__(256) void reduce_kernel(const float* __restrict__ rowLoss,
                                                     float* __restrict__ out, int N) {
    __shared__ float sF[4];
    __shared__ int sI[4];
    int tid = threadIdx.x;
    float sumL = 0.f;
    int nValid = 0, nAcc = 0;
    for (int j = tid; j < N; j += 256) {
        float L = rowLoss[j];
        if (L != BIGV) {
            sumL += L;
            ++nValid;
            if (L < 0.6f) ++nAcc;
        }
    }
    sumL = blockReduceSumF(sumL, sF);
    nValid = blockReduceSumI(nValid, sI);
    nAcc = blockReduceSumI(nAcc, sI);
    if (tid == 0) {
        out[0] = (nValid > 0) ? sumL / (float)nValid : 0.f;
        out[1] = (float)nAcc / (float)N;
        out[2] = 0.f;
        out[3] = 0.f;
    }
}

// ---------------------------------------------------------------------------
extern "C" void kernel_launch(void* const* d_in, const int* in_sizes, int n_in,
                              void* d_out, int out_size, void* d_ws, size_t ws_size,
                              hipStream_t stream) {
    const float* X = (const float*)d_in[0];
    const int* targets = (const int*)d_in[1];
    float* out = (float*)d_out;

    int N = in_sizes[1];             // 4096
    int D = in_sizes[0] / N;         // 1024

    float* dist    = (float*)d_ws;                    // N*N f32  (64 MB)
    float* sq      = dist + (size_t)N * N;            // N f32
    float* rowLoss = sq + N;                          // N f32
    ushort* Xb     = (ushort*)(rowLoss + N);          // N*D bf16 (8 MB)

    prep_kernel<<<N, 256, 0, stream>>>(X, Xb, sq, D);

    dim3 grid(N / GBM, N / GBM);
    distgemm_mfma<<<grid, 256, 0, stream>>>(Xb, sq, dist, N, D);

    rowfinal_kernel<<<N, 256, 0, stream>>>(dist, targets, rowLoss, N);

    reduce_kernel<<<1, 256, 0, stream>>>(rowLoss, out, N);
}